// Round 1
// 348.201 us; speedup vs baseline: 1.0028x; 1.0028x over previous
//
#include <hip/hip_runtime.h>
#include <math.h>

#define B 8
#define M 8192
#define N 512
#define R 256
#define EPSF 1e-16f

typedef __attribute__((ext_vector_type(8))) short short8;
typedef __attribute__((ext_vector_type(16))) float f32x16;

__device__ __forceinline__ unsigned short bf16_rtn(float f) {
    unsigned int u = __float_as_uint(f);
    u += 0x7FFFu + ((u >> 16) & 1u);
    return (unsigned short)(u >> 16);
}

// async global->LDS, 16B per lane. LDS dest = wave-uniform base + lane*16.
__device__ __forceinline__ void gll16(const unsigned short* g, unsigned short* l) {
    __builtin_amdgcn_global_load_lds(
        (const __attribute__((address_space(1))) unsigned int*)g,
        (__attribute__((address_space(3))) unsigned int*)l, 16, 0, 0);
}

// ---------------------------------------------------------------------------
// Kc: gather centers x[b, inds, :] -> c_hi/c_lo (split bf16) + exact fp32 v2.
// ---------------------------------------------------------------------------
__global__ __launch_bounds__(256) void ekm_kc(
    const float* __restrict__ x, const int* __restrict__ inds,
    unsigned short* __restrict__ c_hi, unsigned short* __restrict__ c_lo,
    float* __restrict__ v2g)
{
    const int t = threadIdx.x, b = blockIdx.y;
    const int r = blockIdx.x * 16 + (t >> 4);
    const int seg = (t & 15) * 32;
    const float* src = x + ((size_t)b * M + inds[r]) * N + seg;
    unsigned short* hd = c_hi + ((size_t)b * R + r) * 512 + seg;
    unsigned short* ld = c_lo + ((size_t)b * R + r) * 512 + seg;
    float vp = 0.f;
#pragma unroll
    for (int c = 0; c < 4; ++c) {
        float4 f0 = *(const float4*)(src + c * 8);
        float4 f1 = *(const float4*)(src + c * 8 + 4);
        float av[8] = {f0.x, f0.y, f0.z, f0.w, f1.x, f1.y, f1.z, f1.w};
        unsigned ph[4], pl[4];
#pragma unroll
        for (int j = 0; j < 4; ++j) {
            vp += av[2*j] * av[2*j] + av[2*j+1] * av[2*j+1];
            unsigned short h0 = bf16_rtn(av[2*j]), h1 = bf16_rtn(av[2*j+1]);
            float r0 = av[2*j]   - __uint_as_float((unsigned)h0 << 16);
            float r1 = av[2*j+1] - __uint_as_float((unsigned)h1 << 16);
            ph[j] = (unsigned)h0 | ((unsigned)h1 << 16);
            pl[j] = (unsigned)bf16_rtn(r0) | ((unsigned)bf16_rtn(r1) << 16);
        }
        *(uint4*)(hd + c * 8) = make_uint4(ph[0], ph[1], ph[2], ph[3]);
        *(uint4*)(ld + c * 8) = make_uint4(pl[0], pl[1], pl[2], pl[3]);
    }
    vp += __shfl_xor(vp, 1); vp += __shfl_xor(vp, 2);
    vp += __shfl_xor(vp, 4); vp += __shfl_xor(vp, 8);
    if ((t & 15) == 0) v2g[b * R + r] = vp;
}

// ---------------------------------------------------------------------------
// K1: split-bf16 32x32x16 MFMA distances + fused softmax.
// 2-phase pipeline: A/B double-buffered LDS, glls for tile t+1 issued before
// MFMA(t), counted s_waitcnt vmcnt(3) (xT store + 2 x-prefetch loads stay in
// flight), ONE barrier per K-step. 80 KB LDS -> 2 blocks/CU.
// ---------------------------------------------------------------------------
__global__ __launch_bounds__(256, 2) void ekm_k1(
    const float* __restrict__ x, const float* __restrict__ alpha_p,
    const unsigned short* __restrict__ c_hi, const unsigned short* __restrict__ c_lo,
    const float* __restrict__ v2g, float* __restrict__ u_out,
    unsigned short* __restrict__ uT, unsigned short* __restrict__ xT,
    float* __restrict__ colsum)
{
    __shared__ unsigned short Bh[2][8192], Bl[2][8192];   // 64 KB dbuf (gll, swizzled)
    __shared__ unsigned short Ah[2][2048], Al[2][2048];   // 16 KB dbuf (ds_write, swizzled)

    const int t = threadIdx.x;
    const int b = blockIdx.y;
    const int m0 = blockIdx.x * 64;
    const int w = t >> 6, l = t & 63, col = l & 31, h5 = l >> 5;
    const int arow = t >> 2, kch = t & 3;
    const int cswz = (t & 3) ^ ((t >> 3) & 3);     // swizzled source chunk for B gll
    const int pswz = (col >> 1) & 3;               // fragment-read chunk XOR (A and B)
    const int aws = arow * 32 + (kch ^ ((arow >> 1) & 3)) * 8;   // A write offset

    const float* ax = x + ((size_t)b * M + m0 + arow) * N + kch * 8;
    const unsigned short* bhs = c_hi + ((size_t)b * R + (t >> 2)) * 512 + cswz * 8;
    const unsigned short* bls = c_lo + ((size_t)b * R + (t >> 2)) * 512 + cswz * 8;

    f32x16 acc[2][2];
    acc[0][0] = (f32x16)0.f; acc[0][1] = (f32x16)0.f;
    acc[1][0] = (f32x16)0.f; acc[1][1] = (f32x16)0.f;

    float x2p = 0.f;
    unsigned ph[4], pl[4];
    float4 a0, a1;

    auto convert = [&](void) {   // a0/a1 -> ph/pl split bf16, exact x2 accum
        float av[8] = {a0.x, a0.y, a0.z, a0.w, a1.x, a1.y, a1.z, a1.w};
#pragma unroll
        for (int j = 0; j < 4; ++j) {
            x2p += av[2*j] * av[2*j] + av[2*j+1] * av[2*j+1];
            unsigned short h0 = bf16_rtn(av[2*j]), h1 = bf16_rtn(av[2*j+1]);
            float r0 = av[2*j]   - __uint_as_float((unsigned)h0 << 16);
            float r1 = av[2*j+1] - __uint_as_float((unsigned)h1 << 16);
            ph[j] = (unsigned)h0 | ((unsigned)h1 << 16);
            pl[j] = (unsigned)bf16_rtn(r0) | ((unsigned)bf16_rtn(r1) << 16);
        }
    };

    auto mfma_tile = [&](int c) {
#pragma unroll
        for (int half = 0; half < 2; ++half) {
            const int pc = (half * 2 + h5) ^ pswz;
            short8 ahf[2], alf[2], bhf[2], blf[2];
#pragma unroll
            for (int tm = 0; tm < 2; ++tm) {
                ahf[tm] = *(const short8*)&Ah[c][(tm*32 + col) * 32 + pc * 8];
                alf[tm] = *(const short8*)&Al[c][(tm*32 + col) * 32 + pc * 8];
            }
#pragma unroll
            for (int tr = 0; tr < 2; ++tr) {
                bhf[tr] = *(const short8*)&Bh[c][(w*64 + tr*32 + col) * 32 + pc * 8];
                blf[tr] = *(const short8*)&Bl[c][(w*64 + tr*32 + col) * 32 + pc * 8];
            }
#pragma unroll
            for (int tm = 0; tm < 2; ++tm)
#pragma unroll
            for (int tr = 0; tr < 2; ++tr) {
                acc[tm][tr] = __builtin_amdgcn_mfma_f32_32x32x16_bf16(ahf[tm], bhf[tr], acc[tm][tr], 0, 0, 0);
                acc[tm][tr] = __builtin_amdgcn_mfma_f32_32x32x16_bf16(ahf[tm], blf[tr], acc[tm][tr], 0, 0, 0);
                acc[tm][tr] = __builtin_amdgcn_mfma_f32_32x32x16_bf16(alf[tm], bhf[tr], acc[tm][tr], 0, 0, 0);
            }
        }
    };

    auto xt_store = [&](int c, int tt) {   // xT[k0+kk][m0..m0+63], coalesced 16B
        int kk = t >> 3, ms = (t & 7) * 8;
        unsigned short vv[8];
#pragma unroll
        for (int i = 0; i < 8; ++i) {
            int row = ms + i;
            vv[i] = Ah[c][row * 32 + (((kk >> 3) ^ ((row >> 1) & 3)) << 3) + (kk & 7)];
        }
        *(uint4*)(xT + ((size_t)b * N + tt * 32 + kk) * M + m0 + ms) =
            make_uint4((unsigned)vv[0] | ((unsigned)vv[1] << 16),
                       (unsigned)vv[2] | ((unsigned)vv[3] << 16),
                       (unsigned)vv[4] | ((unsigned)vv[5] << 16),
                       (unsigned)vv[6] | ((unsigned)vv[7] << 16));
    };

    // ---- prologue: stage tile 0, prefetch tile 1 ----
    a0 = *(const float4*)(ax);
    a1 = *(const float4*)(ax + 4);
    convert();
#pragma unroll
    for (int i = 0; i < 4; ++i) {
        gll16(bhs + i * (64 * 512), &Bh[0][i * 2048 + t * 8]);
        gll16(bls + i * (64 * 512), &Bl[0][i * 2048 + t * 8]);
    }
    __builtin_amdgcn_sched_barrier(0);   // glls stay ahead of the loads below
    *(uint4*)&Ah[0][aws] = make_uint4(ph[0], ph[1], ph[2], ph[3]);
    *(uint4*)&Al[0][aws] = make_uint4(pl[0], pl[1], pl[2], pl[3]);
    a0 = *(const float4*)(ax + 32);
    a1 = *(const float4*)(ax + 36);
    asm volatile("s_waitcnt vmcnt(2) lgkmcnt(0)" ::: "memory");
    __builtin_amdgcn_s_barrier();
    __builtin_amdgcn_sched_barrier(0);

    // ---- main loop body: compute tile tt from buf[c], stage tt+1 into buf[nb] ----
    auto body = [&](int tt, int c, int nb) {
        convert();                                   // tile tt+1 (regs -> ph/pl)
#pragma unroll
        for (int i = 0; i < 4; ++i) {                // stage B tile tt+1 (8 glls)
            gll16(bhs + (tt + 1) * 32 + i * (64 * 512), &Bh[nb][i * 2048 + t * 8]);
            gll16(bls + (tt + 1) * 32 + i * (64 * 512), &Bl[nb][i * 2048 + t * 8]);
        }
        __builtin_amdgcn_sched_barrier(0);           // pin: glls precede the 3 vmem ops below
        *(uint4*)&Ah[nb][aws] = make_uint4(ph[0], ph[1], ph[2], ph[3]);
        *(uint4*)&Al[nb][aws] = make_uint4(pl[0], pl[1], pl[2], pl[3]);
        const int pf = (tt + 2 < 16 ? tt + 2 : 15) * 32;   // clamp keeps vmem count uniform
        a0 = *(const float4*)(ax + pf);              // prefetch x tile tt+2 (2 loads)
        a1 = *(const float4*)(ax + pf + 4);
        xt_store(c, tt);                             // 1 store
        mfma_tile(c);
        // drain the 8 glls (oldest); leave store + 2 prefetch loads in flight
        asm volatile("s_waitcnt vmcnt(3) lgkmcnt(0)" ::: "memory");
        __builtin_amdgcn_s_barrier();
        __builtin_amdgcn_sched_barrier(0);
    };

#pragma unroll 1
    for (int tp = 0; tp < 7; ++tp) {
        body(2 * tp, 0, 1);
        body(2 * tp + 1, 1, 0);
    }
    body(14, 0, 1);
    mfma_tile(1);        // peeled tile 15
    xt_store(1, 15);

    // ---- epilogue (reduction scratch aliases dead halves of the LDS bufs) ----
    float* x2s = (float*)&Al[0][0];                       // 256 B
    float (*redm)[64] = (float (*)[64])&Bh[0][0];         // 1 KB
    float (*reds)[64] = (float (*)[64])&Bh[0][2048];      // 1 KB

    x2p += __shfl_xor(x2p, 1);
    x2p += __shfl_xor(x2p, 2);
    if (kch == 0) x2s[arow] = x2p;
    __syncthreads();

    const float ia = 1.4426950408889634f / alpha_p[0];  // log2(e)/alpha
    float v2c[2];
#pragma unroll
    for (int tr = 0; tr < 2; ++tr)
        v2c[tr] = v2g[b * R + w * 64 + tr * 32 + col];

    // d = relu(x2 - 2xv + v2); wave-local row min; stage to LDS
#pragma unroll
    for (int tm = 0; tm < 2; ++tm)
#pragma unroll
    for (int reg = 0; reg < 16; ++reg) {
        int rowl = (reg & 3) + 8 * (reg >> 2) + 4 * h5;
        float x2v = x2s[tm * 32 + rowl];
        float mn;
#pragma unroll
        for (int tr = 0; tr < 2; ++tr) {
            float d = x2v - 2.f * acc[tm][tr][reg] + v2c[tr];
            d = fmaxf(d, 0.f);
            acc[tm][tr][reg] = d;
            mn = (tr == 0) ? d : fminf(mn, d);
        }
        mn = fminf(mn, __shfl_xor(mn, 1));
        mn = fminf(mn, __shfl_xor(mn, 2));
        mn = fminf(mn, __shfl_xor(mn, 4));
        mn = fminf(mn, __shfl_xor(mn, 8));
        mn = fminf(mn, __shfl_xor(mn, 16));
        if (col == 0) redm[w][tm * 32 + rowl] = mn;
    }
    __syncthreads();

    // exp + row sum
#pragma unroll
    for (int tm = 0; tm < 2; ++tm)
#pragma unroll
    for (int reg = 0; reg < 16; ++reg) {
        int m = tm * 32 + (reg & 3) + 8 * (reg >> 2) + 4 * h5;
        float mn = fminf(fminf(redm[0][m], redm[1][m]), fminf(redm[2][m], redm[3][m]));
        float s = 0.f;
#pragma unroll
        for (int tr = 0; tr < 2; ++tr) {
            float e = exp2f((mn - acc[tm][tr][reg]) * ia);
            acc[tm][tr][reg] = e;
            s += e;
        }
        s += __shfl_xor(s, 1); s += __shfl_xor(s, 2); s += __shfl_xor(s, 4);
        s += __shfl_xor(s, 8); s += __shfl_xor(s, 16);
        if (col == 0) reds[w][m] = s;
    }
    __syncthreads();

    // normalize, write u (fp32), accumulate colsum, pack uT (bf16)
    float* ub = u_out + ((size_t)b * M + m0) * R + w * 64;
    float cs[2] = {0.f, 0.f};
#pragma unroll
    for (int tm = 0; tm < 2; ++tm)
#pragma unroll
    for (int reg = 0; reg < 16; ++reg) {
        int rowl = (reg & 3) + 8 * (reg >> 2) + 4 * h5;
        int m = tm * 32 + rowl;
        float inv = 1.f / (reds[0][m] + reds[1][m] + reds[2][m] + reds[3][m]);
#pragma unroll
        for (int tr = 0; tr < 2; ++tr) {
            float uu = acc[tm][tr][reg] * inv;
            acc[tm][tr][reg] = uu;
            ub[(size_t)m * R + tr * 32 + col] = uu;
            cs[tr] += uu;
        }
    }
    unsigned short* uTb = uT + ((size_t)b * R + w * 64) * M + m0;
#pragma unroll
    for (int tm = 0; tm < 2; ++tm)
#pragma unroll
    for (int tr = 0; tr < 2; ++tr)
#pragma unroll
    for (int rq = 0; rq < 4; ++rq) {
        uint2 p;
        p.x = (unsigned)bf16_rtn(acc[tm][tr][rq*4+0]) | ((unsigned)bf16_rtn(acc[tm][tr][rq*4+1]) << 16);
        p.y = (unsigned)bf16_rtn(acc[tm][tr][rq*4+2]) | ((unsigned)bf16_rtn(acc[tm][tr][rq*4+3]) << 16);
        *(uint2*)(uTb + (size_t)(tr*32 + col) * M + tm*32 + 8*rq + 4*h5) = p;
    }
    cs[0] += __shfl_xor(cs[0], 32);
    cs[1] += __shfl_xor(cs[1], 32);
    if (h5 == 0) {
        atomicAdd(&colsum[b * R + w * 64 + col], cs[0]);
        atomicAdd(&colsum[b * R + w * 64 + 32 + col], cs[1]);
    }
}

// ---------------------------------------------------------------------------
// K2: part[slab][b][n][r] = sum_{m in slab} xT[n][m]*uT[r][m].
// 2-phase pipeline: K-step 64, 64 KB double-buffered LDS, glls for tile t+1
// issued before MFMA(t), one vmcnt(0)+barrier per K-step (hidden by MFMA).
// ---------------------------------------------------------------------------
__global__ __launch_bounds__(256, 2) void ekm_k2(
    const unsigned short* __restrict__ xT, const unsigned short* __restrict__ uT,
    float* __restrict__ part)
{
    __shared__ unsigned short XA[2][8192], UB[2][8192];   // 64 KB dbuf
    const int t = threadIdx.x;
    const int nt = blockIdx.x >> 1, rt = blockIdx.x & 1;
    const int slab = blockIdx.y, b = blockIdx.z;
    const int n0 = nt * 128, r0 = rt * 128;
    const int w = t >> 6, l = t & 63, col = l & 31, h5 = l >> 5;
    const int wn = w >> 1, wr = w & 1;
    const int srow = t >> 3;                     // staged row within 32-row group
    const int chunk = (t & 7) ^ (srow & 7);      // pre-swizzled source k-chunk
    const int rx = col & 7;                      // fragment-read chunk XOR

    const unsigned short* xs = xT + ((size_t)b * N + n0 + srow) * M + (size_t)slab * 1024 + chunk * 8;
    const unsigned short* us = uT + ((size_t)b * R + r0 + srow) * M + (size_t)slab * 1024 + chunk * 8;

    f32x16 acc[2][2];
    acc[0][0] = (f32x16)0.f; acc[0][1] = (f32x16)0.f;
    acc[1][0] = (f32x16)0.f; acc[1][1] = (f32x16)0.f;

    // prologue: stage tile 0
#pragma unroll
    for (int i = 0; i < 4; ++i) {
        gll16(xs + (size_t)i * 32 * M, &XA[0][i * 2048 + t * 8]);
        gll16(us + (size_t)i * 32 * M, &UB[0][i * 2048 + t * 8]);
    }
    asm volatile("s_waitcnt vmcnt(0)" ::: "memory");
    __builtin_amdgcn_s_barrier();
    __builtin_amdgcn_sched_barrier(0);

    auto body = [&](int tt, int c, int nb, bool stage) {
        if (stage) {
#pragma unroll
            for (int i = 0; i < 4; ++i) {        // stage tile tt+1 (8 glls)
                gll16(xs + (tt + 1) * 64 + (size_t)i * 32 * M, &XA[nb][i * 2048 + t * 8]);
                gll16(us + (tt + 1) * 64 + (size_t)i * 32 * M, &UB[nb][i * 2048 + t * 8]);
            }
            __builtin_amdgcn_sched_barrier(0);
        }
#pragma unroll
        for (int kk = 0; kk < 4; ++kk) {
            const int pc = (kk * 2 + h5) ^ rx;
            short8 af[2], bf2[2];
#pragma unroll
            for (int tm = 0; tm < 2; ++tm)
                af[tm] = *(const short8*)&XA[c][(wn*64 + tm*32 + col) * 64 + pc * 8];
#pragma unroll
            for (int tr = 0; tr < 2; ++tr)
                bf2[tr] = *(const short8*)&UB[c][(wr*64 + tr*32 + col) * 64 + pc * 8];
#pragma unroll
            for (int tm = 0; tm < 2; ++tm)
#pragma unroll
            for (int tr = 0; tr < 2; ++tr)
                acc[tm][tr] = __builtin_amdgcn_mfma_f32_32x32x16_bf16(af[tm], bf2[tr], acc[tm][tr], 0, 0, 0);
        }
        if (stage) {
            asm volatile("s_waitcnt vmcnt(0)" ::: "memory");
            __builtin_amdgcn_s_barrier();
            __builtin_amdgcn_sched_barrier(0);
        }
    };

#pragma unroll 1
    for (int tp = 0; tp < 7; ++tp) {
        body(2 * tp, 0, 1, true);
        body(2 * tp + 1, 1, 0, true);
    }
    body(14, 0, 1, true);
    body(15, 1, 0, false);

    float* pb = part + (size_t)slab * ((size_t)B * N * R) + (size_t)b * N * R;
#pragma unroll
    for (int tm = 0; tm < 2; ++tm)
#pragma unroll
    for (int reg = 0; reg < 16; ++reg) {
        int n = n0 + wn*64 + tm*32 + (reg & 3) + 8*(reg >> 2) + 4*h5;
#pragma unroll
        for (int tr = 0; tr < 2; ++tr)
            pb[(size_t)n * R + r0 + wr*64 + tr*32 + col] = acc[tm][tr][reg];
    }
}

// ---------------------------------------------------------------------------
// Kred: v = (sum of 8 partial slabs) / (colsum + eps), float4 per thread.
// ---------------------------------------------------------------------------
__global__ __launch_bounds__(256) void ekm_red(
    const float* __restrict__ part, const float* __restrict__ colsum,
    float* __restrict__ v_out)
{
    size_t o = ((size_t)blockIdx.x * 256 + threadIdx.x) * 4;
    float sx = 0.f, sy = 0.f, sz = 0.f, sw = 0.f;
#pragma unroll
    for (int sl = 0; sl < 8; ++sl) {
        float4 p = *(const float4*)(part + (size_t)sl * B * N * R + o);
        sx += p.x; sy += p.y; sz += p.z; sw += p.w;
    }
    int b = (int)(o >> 17);           // N*R = 131072
    int r = (int)(o & (R - 1));
    float4 cs = *(const float4*)(colsum + b * R + r);
    float4 vo;
    vo.x = sx / (cs.x + EPSF);
    vo.y = sy / (cs.y + EPSF);
    vo.z = sz / (cs.z + EPSF);
    vo.w = sw / (cs.w + EPSF);
    *(float4*)(v_out + o) = vo;
}

extern "C" void kernel_launch(void* const* d_in, const int* in_sizes, int n_in,
                              void* d_out, int out_size, void* d_ws, size_t ws_size,
                              hipStream_t stream) {
    const float* x     = (const float*)d_in[0];
    const float* alpha = (const float*)d_in[1];
    const int*   inds  = (const int*)d_in[2];

    float* u_out = (float*)d_out;                    // B*M*R fp32
    float* v_out = u_out + (size_t)B * M * R;        // B*N*R fp32

    char* ws = (char*)d_ws;
    const size_t CH = (size_t)B * R * 512 * 2;       // 2 MB   c_hi / c_lo
    unsigned short* c_hi   = (unsigned short*)ws;
    unsigned short* c_lo   = (unsigned short*)(ws + CH);
    float*          v2g    = (float*)(ws + 2 * CH);
    float*          colsum = (float*)(ws + 2 * CH + (size_t)B * R * 4);
    char* p = ws + 2 * CH + 2 * (size_t)B * R * 4;
    unsigned short* xT = (unsigned short*)p;          p += (size_t)B * N * M * 2;  // 67 MB
    unsigned short* uT = (unsigned short*)p;          p += (size_t)B * R * M * 2;  // 33.5 MB
    float*          part = (float*)p;                 // 8 * B*N*R * 4 = 33.5 MB

    hipMemsetAsync(colsum, 0, (size_t)B * R * sizeof(float), stream);

    ekm_kc<<<dim3(16, B), 256, 0, stream>>>(x, inds, c_hi, c_lo, v2g);
    ekm_k1<<<dim3(M / 64, B), 256, 0, stream>>>(x, alpha, c_hi, c_lo, v2g,
                                                u_out, uT, xT, colsum);
    ekm_k2<<<dim3(8, 8, B), 256, 0, stream>>>(xT, uT, part);
    ekm_red<<<(B * N * R / 4) / 256, 256, 0, stream>>>(part, colsum, v_out);
}